// Round 4
// baseline (40.245 us; speedup 1.0000x reference)
//
#include <hip/hip_runtime.h>
#include <math.h>

#define NUM_CLASSES 15
#define NUM_ANCHORS 18
#define NC6 21            // NUM_CLASSES + 6
#define GRID 64
#define BATCH 16

typedef float f32x4 __attribute__((ext_vector_type(4)));

__device__ __forceinline__ float sigmoidf_fast(float v) {
    return 1.0f / (1.0f + __expf(-v));
}

// One block per (b, a, y) group. Group = 21 channels x 64 x-values.
// q in [0,336): c = q>>4, xs = (q&15)*4.
// LDS scatter idx = (xs+k)*21+c: lane stride 84 -> 2 lanes/bank across the
// wave (measured-free on CDNA4); LDS read side is linear b128, conflict-free.
// Input:  in[((b*378 + a*21 + c)*64 + y)*64 + x]   (c stride = 4096 floats)
// Output: out[(b*73728 + a*4096 + y*64 + x)*21 + c] (c contiguous)
__launch_bounds__(256)
__global__ void yolo_layer_kernel(const float* __restrict__ in,
                                  const float* __restrict__ anchors,
                                  float* __restrict__ out) {
    const int gid = blockIdx.x;                 // 0 .. 16*18*64-1
    const int y   = gid & (GRID - 1);
    const int a   = (gid >> 6) % NUM_ANCHORS;
    const int b   = gid / (GRID * NUM_ANCHORS);

    __shared__ float lds[GRID * NC6];           // 1344 floats = 5376 B

    const float aw8 = anchors[a * 3 + 0] * 8.0f;
    const float ah8 = anchors[a * 3 + 1] * 8.0f;
    const float aa  = anchors[a * 3 + 2];

    const int base_in  = (b * (NUM_ANCHORS * NC6) + a * NC6) * (GRID * GRID) + y * GRID;
    const int base_out = gid * (GRID * NC6);

    const int   t  = threadIdx.x;
    const float fy = (float)y;

    // ---- load + transform + LDS transpose scatter: 336 float4 per block ----
    #pragma unroll
    for (int q0 = 0; q0 < 2; ++q0) {
        int q = q0 * 256 + t;
        if (q < (NC6 * GRID / 4)) {             // 336
            int c  = q >> 4;                    // 16 float4 per 64-float row
            int xs = (q & 15) << 2;
            const float* p = in + base_in + c * (GRID * GRID) + xs;
            f32x4 v = __builtin_nontemporal_load(reinterpret_cast<const f32x4*>(p));
            #pragma unroll
            for (int k = 0; k < 4; ++k) {
                float vk = v[k];
                float r;
                if (c >= 5) {
                    r = sigmoidf_fast(vk);                                   // conf + cls
                } else if (c == 0) {
                    r = (sigmoidf_fast(vk) * 1.05f - 0.025f + (float)(xs + k)) * 8.0f;
                } else if (c == 1) {
                    r = (sigmoidf_fast(vk) * 1.05f - 0.025f + fy) * 8.0f;
                } else if (c == 2) {
                    r = __expf(vk) * aw8;
                } else if (c == 3) {
                    r = __expf(vk) * ah8;
                } else {                                                     // c == 4
                    r = vk + aa;
                }
                lds[(xs + k) * NC6 + c] = r;
            }
        }
    }
    __syncthreads();

    // ---- contiguous coalesced float4 streaming store of the whole group ----
    #pragma unroll
    for (int q0 = 0; q0 < 2; ++q0) {
        int q = q0 * 256 + t;
        if (q < (NC6 * GRID / 4)) {             // 336
            f32x4 v = *reinterpret_cast<const f32x4*>(&lds[q * 4]);
            __builtin_nontemporal_store(v, reinterpret_cast<f32x4*>(out + base_out + q * 4));
        }
    }
}

extern "C" void kernel_launch(void* const* d_in, const int* in_sizes, int n_in,
                              void* d_out, int out_size, void* d_ws, size_t ws_size,
                              hipStream_t stream) {
    const float* in      = (const float*)d_in[0];
    const float* anchors = (const float*)d_in[1];
    float* out           = (float*)d_out;

    const int n_groups = BATCH * NUM_ANCHORS * GRID;   // 18432
    yolo_layer_kernel<<<dim3(n_groups), dim3(256), 0, stream>>>(in, anchors, out);
}

// Round 5
// 35.664 us; speedup vs baseline: 1.1284x; 1.1284x over previous
//
#include <hip/hip_runtime.h>
#include <math.h>

#define NUM_CLASSES 15
#define NUM_ANCHORS 18
#define NC6 21            // NUM_CLASSES + 6
#define GRID 64
#define BATCH 16

typedef float f32x4 __attribute__((ext_vector_type(4)));

__device__ __forceinline__ float sigmoidf_fast(float v) {
    return 1.0f / (1.0f + __expf(-v));
}

// One block per (b, a, y0..y0+3); wave w owns row y0+w with a PRIVATE LDS
// segment -> no __syncthreads needed (same-wave DS ops are in program order).
// Per wave: qq in [0,336): c = qq>>4, xs = (qq&15)*4.
// LDS scatter idx = (xs+k)*21+c: lane stride 84 -> 2 lanes/bank (free);
// read side linear b128, conflict-free. No nontemporal (measured -3.5us).
// Input:  in[((b*378 + a*21 + c)*64 + y)*64 + x]   (c stride = 4096 floats)
// Output: out[(b*73728 + a*4096 + y*64 + x)*21 + c] (c contiguous)
__launch_bounds__(256)
__global__ void yolo_layer_kernel(const float* __restrict__ in,
                                  const float* __restrict__ anchors,
                                  float* __restrict__ out) {
    const int g  = blockIdx.x;                  // 0 .. 4607
    const int y0 = (g & 15) << 2;
    const int a  = (g >> 4) % NUM_ANCHORS;
    const int b  = g / (16 * NUM_ANCHORS);

    const int w    = threadIdx.x >> 6;          // wave id 0..3 -> row offset
    const int lane = threadIdx.x & 63;
    const int y    = y0 + w;

    __shared__ float lds[4][GRID * NC6];        // 4 x 5376 B, wave-private rows

    const float aw8 = anchors[a * 3 + 0] * 8.0f;
    const float ah8 = anchors[a * 3 + 1] * 8.0f;
    const float aa  = anchors[a * 3 + 2];

    const int base_in  = (b * (NUM_ANCHORS * NC6) + a * NC6) * (GRID * GRID) + y * GRID;
    const int base_out = ((b * NUM_ANCHORS + a) * (GRID * GRID) + y * GRID) * NC6;

    const float fy = (float)y;

    // ---- load + transform + LDS transpose scatter: 336 float4 per wave ----
    #pragma unroll
    for (int i = 0; i < 6; ++i) {
        int qq = i * 64 + lane;
        if (qq < (NC6 * GRID / 4)) {            // 336
            int c  = qq >> 4;                   // 16 float4 per 64-float row
            int xs = (qq & 15) << 2;
            f32x4 v = *reinterpret_cast<const f32x4*>(in + base_in + c * (GRID * GRID) + xs);
            #pragma unroll
            for (int k = 0; k < 4; ++k) {
                float vk = v[k];
                float r;
                if (c >= 5) {
                    r = sigmoidf_fast(vk);                                   // conf + cls
                } else if (c == 0) {
                    r = (sigmoidf_fast(vk) * 1.05f - 0.025f + (float)(xs + k)) * 8.0f;
                } else if (c == 1) {
                    r = (sigmoidf_fast(vk) * 1.05f - 0.025f + fy) * 8.0f;
                } else if (c == 2) {
                    r = __expf(vk) * aw8;
                } else if (c == 3) {
                    r = __expf(vk) * ah8;
                } else {                                                     // c == 4
                    r = vk + aa;
                }
                lds[w][(xs + k) * NC6 + c] = r;
            }
        }
    }

    // no __syncthreads: each wave reads only its own LDS segment

    // ---- contiguous coalesced float4 store of the wave's row ----
    #pragma unroll
    for (int i = 0; i < 6; ++i) {
        int qq = i * 64 + lane;
        if (qq < (NC6 * GRID / 4)) {            // 336
            f32x4 v = *reinterpret_cast<const f32x4*>(&lds[w][qq * 4]);
            *reinterpret_cast<f32x4*>(out + base_out + qq * 4) = v;
        }
    }
}

extern "C" void kernel_launch(void* const* d_in, const int* in_sizes, int n_in,
                              void* d_out, int out_size, void* d_ws, size_t ws_size,
                              hipStream_t stream) {
    const float* in      = (const float*)d_in[0];
    const float* anchors = (const float*)d_in[1];
    float* out           = (float*)d_out;

    const int n_groups = BATCH * NUM_ANCHORS * (GRID / 4);   // 4608
    yolo_layer_kernel<<<dim3(n_groups), dim3(256), 0, stream>>>(in, anchors, out);
}